// Round 6
// baseline (767.194 us; speedup 1.0000x reference)
//
#include <hip/hip_runtime.h>

// Problem constants (match reference)
#define NX_ 432
#define NY_ 496
#define C_  64
#define B_  4
#define CELLS_ (NX_ * NY_)            // 214272 cells per (bin, batch) canvas plane
#define PLANE_ ((size_t)CELLS_)       // c-plane stride in floats
#define BATCH_STRIDE_ ((size_t)C_ * CELLS_)        // 13,713,408 floats
#define BIN_STRIDE_   ((size_t)B_ * C_ * CELLS_)   // 54,853,632 floats
#define MAP_BIN_ ((size_t)B_ * CELLS_)             // map entries per bin

typedef float vfloat4 __attribute__((ext_vector_type(4)));
typedef int   vint4   __attribute__((ext_vector_type(4)));

// ---------------------------------------------------------------------------
// Kernel 1: scatter pillar index p into map[bin][b*CELLS + z + y*NX + x]
// ---------------------------------------------------------------------------
__global__ __launch_bounds__(256) void scatter_idx_kernel(
    const int* __restrict__ coords0,
    const int* __restrict__ coords1,
    const int* __restrict__ coords2,
    int* __restrict__ map, int npil)
{
    const int bin = blockIdx.y;
    const int p = blockIdx.x * 256 + threadIdx.x;
    if (p >= npil) return;
    const int* coords = (bin == 0) ? coords0 : (bin == 1) ? coords1 : coords2;
    vint4 c = ((const vint4*)coords)[p];
    size_t idx = (size_t)bin * MAP_BIN_ + (size_t)c.x * CELLS_ + c.y + c.z * NX_ + c.w;
    map[idx] = p;
}

// ---------------------------------------------------------------------------
// Kernel 2 — ROUND 6 DIAGNOSTIC BUILD (correctness-preserving).
//
// Identical to the 684 us round-5 plane-group-split gather, EXCEPT:
//  * all loads are hoisted before an npass store-replay loop;
//  * passes 1..npass-1 re-store the SAME values to the SAME addresses
//    (pstride == 0 at runtime, opaque to the compiler -> no dead-store
//    elimination, no cross-pass merging).
//
// Purpose: (a) the gather dispatch exceeds the ~425 us poison fills and
// surfaces in the top-5 counter table for the FIRST direct FETCH_SIZE /
// WRITE_SIZE / occupancy reading; (b) passes 2..3 are PURE-WRITE replays
// of the exact 658 MB store pattern, so T_pure = (dur_total - 684)/2
// measures the write-side ceiling of this pattern in isolation.
// Output is written with correct values every pass -> absmax 0 preserved.
// ---------------------------------------------------------------------------
__global__ __launch_bounds__(256) void gather_split_kernel(
    const float* __restrict__ pf0,
    const float* __restrict__ pf1,
    const float* __restrict__ pf2,
    const int* __restrict__ map,
    float* __restrict__ out,
    int npass, size_t pstride)
{
    const int g   = blockIdx.y;           // plane-group: channels 4g..4g+3
    const int zb  = blockIdx.z;           // bin*B_ + b
    const int bin = zb >> 2;
    const int b   = zb & 3;

    const int cell = blockIdx.x * 1024 + threadIdx.x * 4;
    if (cell >= CELLS_) return;

    const float* __restrict__ pf = (bin == 0) ? pf0 : (bin == 1) ? pf1 : pf2;

    const int* m = map + (size_t)bin * MAP_BIN_ + (size_t)b * CELLS_ + cell;
    vint4 idx = *(const vint4*)m;

    const bool v0 = idx.x >= 0, v1 = idx.y >= 0, v2 = idx.z >= 0, v3 = idx.w >= 0;
    // Clamp invalid to row 0: always-safe address, unconditional 16B loads.
    const vfloat4 x0 = *(const vfloat4*)(pf + (size_t)(v0 ? idx.x : 0) * C_ + 4 * g);
    const vfloat4 x1 = *(const vfloat4*)(pf + (size_t)(v1 ? idx.y : 0) * C_ + 4 * g);
    const vfloat4 x2 = *(const vfloat4*)(pf + (size_t)(v2 ? idx.z : 0) * C_ + 4 * g);
    const vfloat4 x3 = *(const vfloat4*)(pf + (size_t)(v3 ? idx.w : 0) * C_ + 4 * g);

    // Resolve selects once; w[] lives in registers across the replay loop.
    vfloat4 w[4];
#pragma unroll
    for (int q = 0; q < 4; ++q) {
        w[q].x = v0 ? x0[q] : 0.0f;
        w[q].y = v1 ? x1[q] : 0.0f;
        w[q].z = v2 ? x2[q] : 0.0f;
        w[q].w = v3 ? x3[q] : 0.0f;
    }

    float* o = out + (size_t)bin * BIN_STRIDE_ + (size_t)b * BATCH_STRIDE_ + cell;

    // Store-replay loop: pass 0 = the real mixed pass; passes 1..npass-1 =
    // pure-write replays (pstride==0 -> same addresses, same values).
    for (int pass = 0; pass < npass; ++pass) {
        float* op = o + (size_t)pass * pstride;   // runtime-opaque, == o
#pragma unroll
        for (int q = 0; q < 4; ++q)
            *(vfloat4*)(op + (size_t)(4 * g + q) * PLANE_) = w[q];
    }
}

extern "C" void kernel_launch(void* const* d_in, const int* in_sizes, int n_in,
                              void* d_out, int out_size, void* d_ws, size_t ws_size,
                              hipStream_t stream) {
    const float* pf0 = (const float*)d_in[0];
    const int*   co0 = (const int*)d_in[1];
    const float* pf1 = (const float*)d_in[2];
    const int*   co1 = (const int*)d_in[3];
    const float* pf2 = (const float*)d_in[4];
    const int*   co2 = (const int*)d_in[5];
    float* out = (float*)d_out;

    const int npil = in_sizes[1] / 4;   // rows in coords (B*P_PER)

    int* map = (int*)d_ws;
    const size_t map_bytes = 3 * MAP_BIN_ * sizeof(int);

    // init map to -1 (0xFFFFFFFF) — ~10 MB, ~2 us
    (void)hipMemsetAsync(map, 0xFF, map_bytes, stream);

    dim3 g1((npil + 255) / 256, 3, 1);
    scatter_idx_kernel<<<g1, 256, 0, stream>>>(co0, co1, co2, map, npil);

    // x: 210 cell-chunks (fastest -> dense write frontier), y: 16 plane-
    // groups, z: 12 (bin,b) pairs.
    // DIAGNOSTIC: npass=3 (1 mixed + 2 pure-write replays), pstride=0.
    dim3 g2((CELLS_ + 1023) / 1024, C_ / 4, 3 * B_);
    gather_split_kernel<<<g2, 256, 0, stream>>>(pf0, pf1, pf2, map, out,
                                                3, (size_t)0);
}